// Round 5
// baseline (5249.632 us; speedup 1.0000x reference)
//
#include <hip/hip_runtime.h>

typedef unsigned int u32;
typedef unsigned short u16;
typedef unsigned long long u64;
typedef _Float16 f16;
typedef _Float16 f16x2 __attribute__((ext_vector_type(2)));

#define Bn 256
#define Sn 200
#define Dn 128
#define Mn 64
#define NQn 5000

__device__ __forceinline__ float fdot2f(u32 w, u32 x, float acc) {
#if __has_builtin(__builtin_amdgcn_fdot2)
    return __builtin_amdgcn_fdot2(__builtin_bit_cast(f16x2, w),
                                  __builtin_bit_cast(f16x2, x), acc, false);
#else
    f16x2 a = __builtin_bit_cast(f16x2, w);
    f16x2 b = __builtin_bit_cast(f16x2, x);
    return acc + (float)a[0] * (float)b[0] + (float)a[1] * (float)b[1];
#endif
}

__device__ __forceinline__ u32 packh2(float a, float b) {
    u16 ua = __builtin_bit_cast(u16, (f16)a);
    u16 ub = __builtin_bit_cast(u16, (f16)b);
    return (u32)ua | ((u32)ub << 16);
}

__device__ __forceinline__ void unp2(u32 v, float& lo, float& hi) {
    lo = (float)__builtin_bit_cast(f16, (u16)(v & 0xffff));
    hi = (float)__builtin_bit_cast(f16, (u16)(v >> 16));
}

__device__ __forceinline__ float fexp2f(float x) {
#if __has_builtin(__builtin_amdgcn_exp2f)
    return __builtin_amdgcn_exp2f(x);
#else
    return exp2f(x);
#endif
}
__device__ __forceinline__ float frcpf(float x) {
#if __has_builtin(__builtin_amdgcn_rcpf)
    return __builtin_amdgcn_rcpf(x);
#else
    return 1.0f / x;
#endif
}
__device__ __forceinline__ float sig_fast(float x)  { return frcpf(1.0f + fexp2f(-1.44269504f * x)); }
__device__ __forceinline__ float tanh_fast(float x) { return fmaf(-2.0f, frcpf(1.0f + fexp2f(2.88539008f * x)), 1.0f); }

// ---- DPP quad helpers -----------------------------------------------------
template<int CTRL>
__device__ __forceinline__ float qdpp(float x) {
    return __builtin_bit_cast(float, __builtin_amdgcn_update_dpp(
        0, __builtin_bit_cast(int, x), CTRL, 0xF, 0xF, true));
}
__device__ __forceinline__ float quad_red(float x) {
    x += qdpp<0xB1>(x);   // quad_perm [1,0,3,2]
    x += qdpp<0x4E>(x);   // quad_perm [2,3,0,1]
    return x;
}

// ---------------------------------------------------------------------------
// Kernel A: cw = softmax(k @ Mk^T) fp32 + iv-code ballots. (R2 shape)
// ---------------------------------------------------------------------------
__global__ __launch_bounds__(512) void phase0_kernel(
    const int* __restrict__ qseq,
    const float* __restrict__ Mk, const float* __restrict__ embc,
    u16* __restrict__ cw16, ulonglong2* __restrict__ codes)
{
    __shared__ float MkT[Dn * 65];
    __shared__ float kb[8][Dn];
    int tid = threadIdx.x;
    for (int idx = tid; idx < Mn * Dn; idx += 512) {
        int m = idx >> 7, d = idx & 127;
        MkT[d * 65 + m] = Mk[idx];
    }
    __syncthreads();
    int w = tid >> 6, lane = tid & 63;
    int item = blockIdx.x * 8 + w;
    int qq = qseq[item];
    kb[w][lane]      = embc[qq * Dn + lane];
    kb[w][lane + 64] = embc[qq * Dn + lane + 64];
    __syncthreads();
    float acc = 0.0f;
    const float* kw = kb[w];
#pragma unroll 8
    for (int d = 0; d < Dn; ++d)
        acc = fmaf(MkT[d * 65 + lane], kw[d], acc);
    float mx = acc;
    for (int off = 32; off; off >>= 1) mx = fmaxf(mx, __shfl_xor(mx, off));
    float e = expf(acc - mx);
    float sm = e;
    for (int off = 32; off; off >>= 1) sm += __shfl_xor(sm, off);
    float cw = e / sm;
    cw16[item * Mn + lane] = __builtin_bit_cast(u16, (f16)cw);
    float t1 = (cw - 0.01f) / (0.05f - 0.01f);
    float t2 = (0.1f - cw) / (0.1f - 0.05f);
    float tri = fmaxf(fminf(t1, t2), 0.0f);
    int iv = (tri >= 0.6f) ? 2 : ((tri >= 0.1f) ? 1 : 0);
    u64 b1 = __ballot(iv >= 1);
    u64 b2 = __ballot(iv == 2);
    if (lane == 0) { codes[item].x = b1; codes[item].y = b2; }
}

// ---------------------------------------------------------------------------
// Kernel B: prev_t match. (unchanged)
// ---------------------------------------------------------------------------
__global__ __launch_bounds__(256) void match_kernel(
    const ulonglong2* __restrict__ codes, int* __restrict__ prev)
{
    __shared__ u64 clo[Sn], chi[Sn];
    int b = blockIdx.x, tid = threadIdx.x;
    if (tid < Sn) { ulonglong2 c = codes[b * Sn + tid]; clo[tid] = c.x; chi[tid] = c.y; }
    __syncthreads();
    if (tid < Sn) {
        u64 mylo = clo[tid], myhi = chi[tid];
        int best = -1;
        for (int j = 0; j < tid; ++j)
            if (clo[j] == mylo && chi[j] == myhi) best = j;
        prev[b * Sn + tid] = best;
    }
}

// ---------------------------------------------------------------------------
// Kernel P: hoisted recurrence-independent matvecs. (R2 shape)
// ---------------------------------------------------------------------------
__global__ __launch_bounds__(512) void pre_kernel(
    const float* __restrict__ W, const float* __restrict__ emb,
    const int* __restrict__ qseq, const int* __restrict__ cseq, int mode,
    u16* __restrict__ outp)
{
    __shared__ u32 wL[128 * 65];
    __shared__ u32 vb[8][64];
    int tid = threadIdx.x;
    for (int idx = tid; idx < 128 * 64; idx += 512) {
        int dd = idx >> 6, jj = idx & 63;
        const float2 wv = *(const float2*)(W + dd * 256 + 128 + 2 * jj);
        wL[dd * 65 + jj] = packh2(wv.x, wv.y);
    }
    int w = tid >> 6, lane = tid & 63;
    int item = blockIdx.x * 8 + w;
    int row = qseq[item];
    if (mode) row += NQn * cseq[item];
    {
        const float2 kv = *(const float2*)(emb + row * Dn + 2 * lane);
        vb[w][lane] = packh2(kv.x, kv.y);
    }
    __syncthreads();
    const u32* w0 = wL + lane * 65;
    const u32* w1 = wL + (64 + lane) * 65;
    const u32* x  = vb[w];
    float a0 = 0, a1 = 0, b0 = 0, b1 = 0;
#pragma unroll
    for (int jj = 0; jj < 64; jj += 2) {
        a0 = fdot2f(w0[jj],     x[jj],     a0);
        a1 = fdot2f(w0[jj + 1], x[jj + 1], a1);
        b0 = fdot2f(w1[jj],     x[jj],     b0);
        b1 = fdot2f(w1[jj + 1], x[jj + 1], b1);
    }
    outp[item * Dn + lane]      = __builtin_bit_cast(u16, (f16)(a0 + a1));
    outp[item * Dn + 64 + lane] = __builtin_bit_cast(u16, (f16)(b0 + b1));
}

// ---------------------------------------------------------------------------
// Kernel F: FUSED memrec + hop-LSTM (v3).
//  ONLY change vs v2: __launch_bounds__(512, 1) -> VGPR cap 256 (was 128,
//  which forced spilling of the ~176-reg persistent weight set to scratch:
//  VGPR_Count==128 + FETCH_SIZE 4.3 GB in R3/R4). 1 block/CU is already
//  forced by LDS (120 KB) and grid==CU count, so no occupancy is lost.
// ---------------------------------------------------------------------------
__global__ __launch_bounds__(512, 1) void fused_kernel(
    const float* __restrict__ Mv0,
    const float* __restrict__ Wf, const float* __restrict__ bfv,
    const float* __restrict__ Wa, const float* __restrict__ bav,
    const float* __restrict__ We, const float* __restrict__ bev,
    const float* __restrict__ Wadd, const float* __restrict__ badv,
    const float* __restrict__ W_ih, const float* __restrict__ W_hh,
    const float* __restrict__ b_ih, const float* __restrict__ b_hh,
    const float* __restrict__ hx0, const float* __restrict__ cx0,
    const float* __restrict__ Wp, const float* __restrict__ bp,
    const u16* __restrict__ cw16, const u16* __restrict__ kf16,
    const u16* __restrict__ ya16, const int* __restrict__ prev,
    float* __restrict__ out)
{
    __shared__ __align__(16) u32 HL[(Sn + 1) * 64];   // 51.4 KB
    __shared__ __align__(16) u32 wewS[4 * 512 * 4];   // 32 KB, consumer-ordered
    __shared__ __align__(16) u32 wadwS[4 * 512 * 4];  // 32 KB
    __shared__ __align__(16) u32 cwb[2][32];
    __shared__ __align__(16) u32 kfb[2][64];
    __shared__ __align__(16) u32 yab[2][64];
    __shared__ __align__(16) u32 rbuf[64], fbuf[64], wbuf[64];
    __shared__ int prevL[Sn];
    __shared__ u32 wpL[64];
    __shared__ float bpL;

    int tid = threadIdx.x, b = blockIdx.x;
    int d = tid >> 2, q = tid & 3;

    // ---- register-resident weights: Wf_read-half, Wa_f-half ----
    u32 wfr[16], waf[16];
    {
        const float2* pf = (const float2*)(Wf + d * 256 + q * 32);
        const float2* pa = (const float2*)(Wa + d * 256 + q * 32);
#pragma unroll
        for (int i = 0; i < 16; ++i) {
            float2 a;
            a = pf[i]; wfr[i] = packh2(a.x, a.y);
            a = pa[i]; waf[i] = packh2(a.x, a.y);
        }
    }
    // ---- We/Wadd -> LDS, consumer order (chunk u, thread tid) ----
    {
        const float2* pe = (const float2*)(We + d * 128 + q * 32);
        const float2* pd = (const float2*)(Wadd + d * 128 + q * 32);
#pragma unroll
        for (int u = 0; u < 4; ++u) {
#pragma unroll
            for (int j = 0; j < 4; ++j) {
                float2 a;
                a = pe[4 * u + j]; wewS[(u * 512 + tid) * 4 + j]  = packh2(a.x, a.y);
                a = pd[4 * u + j]; wadwS[(u * 512 + tid) * 4 + j] = packh2(a.x, a.y);
            }
        }
    }
    int r = q * 128 + d;                     // lstm gate row (i,f,g,o)
    u32 wih[64], whh[64];
    {
        const float2* wi2 = (const float2*)(W_ih + r * Dn);
        const float2* wh2 = (const float2*)(W_hh + r * Dn);
#pragma unroll
        for (int i = 0; i < 64; ++i) {
            float2 a;
            a = wi2[i]; wih[i] = packh2(a.x, a.y);
            a = wh2[i]; whh[i] = packh2(a.x, a.y);
        }
    }
    float memv[16];
#pragma unroll
    for (int i = 0; i < 16; ++i) memv[i] = Mv0[(q * 16 + i) * Dn + d];
    float vbf = bfv[d], vba = bav[d], vbe = bev[d], vbad = badv[d];
    float vbsum = b_ih[r] + b_hh[r];
    float cx = cx0[d];

    if (tid < 64) {
        HL[tid]  = packh2(hx0[2 * tid], hx0[2 * tid + 1]);
        wpL[tid] = packh2(Wp[2 * tid], Wp[2 * tid + 1]);
    }
    { int u = tid - 64;  if (u >= 0 && u < 32) cwb[0][u] = ((const u32*)cw16)[(b * Sn) * 32 + u]; }
    { int u = tid - 96;  if (u >= 0 && u < 64) kfb[0][u] = ((const u32*)kf16)[(size_t)(b * Sn) * 64 + u]; }
    { int u = tid - 160; if (u >= 0 && u < 64) yab[0][u] = ((const u32*)ya16)[(size_t)(b * Sn) * 64 + u]; }
    if (tid < Sn) prevL[tid] = prev[b * Sn + tid];
    if (tid == 0) bpL = bp[0];
    __syncthreads();

    int pu = tid - 352;          // prefetch role: 0..159 (32 cw + 64 kf + 64 ya)
    u32 pfv = 0;

    for (int t = 0; t < Sn; ++t) {
        int cur = t & 1;
        // ===== P1: memrec read partial (+issue t+1 prefetch loads) =========
        {
            float lo, hi;
            float p0 = 0, p1 = 0, p2 = 0, p3 = 0;
            uint4 cA = ((const uint4*)cwb[cur])[2 * q];
            uint4 cB = ((const uint4*)cwb[cur])[2 * q + 1];
            unp2(cA.x, lo, hi); p0 = fmaf(lo, memv[0], p0); p1 = fmaf(hi, memv[1], p1);
            unp2(cA.y, lo, hi); p2 = fmaf(lo, memv[2], p2); p3 = fmaf(hi, memv[3], p3);
            unp2(cA.z, lo, hi); p0 = fmaf(lo, memv[4], p0); p1 = fmaf(hi, memv[5], p1);
            unp2(cA.w, lo, hi); p2 = fmaf(lo, memv[6], p2); p3 = fmaf(hi, memv[7], p3);
            unp2(cB.x, lo, hi); p0 = fmaf(lo, memv[8], p0); p1 = fmaf(hi, memv[9], p1);
            unp2(cB.y, lo, hi); p2 = fmaf(lo, memv[10], p2); p3 = fmaf(hi, memv[11], p3);
            unp2(cB.z, lo, hi); p0 = fmaf(lo, memv[12], p0); p1 = fmaf(hi, memv[13], p1);
            unp2(cB.w, lo, hi); p2 = fmaf(lo, memv[14], p2); p3 = fmaf(hi, memv[15], p3);
            float pr = quad_red((p0 + p1) + (p2 + p3));
            if (q == 0) ((u16*)rbuf)[d] = __builtin_bit_cast(u16, (f16)pr);
        }
        if (t + 1 < Sn && pu >= 0) {
            if (pu < 32)      pfv = ((const u32*)cw16)[(b * Sn + t + 1) * 32 + pu];
            else if (pu < 96) pfv = ((const u32*)kf16)[(size_t)(b * Sn + t + 1) * 64 + (pu - 32)];
            else              pfv = ((const u32*)ya16)[(size_t)(b * Sn + t + 1) * 64 + (pu - 96)];
        }
        int pv = prevL[t];
        int hrow = (pv >= 0) ? (pv + 1) : t;
        __syncthreads();                                     // B1
        // ===== P2: memrec f  +  lstm W_hh·h dot ============================
        float b0 = 0, b1 = 0, b2 = 0, b3 = 0;
        {
            const uint4* h4 = (const uint4*)(HL + hrow * 64);
#pragma unroll
            for (int u = 0; u < 16; ++u) {
                uint4 x = h4[u];
                b0 = fdot2f(whh[4 * u + 0], x.x, b0);
                b1 = fdot2f(whh[4 * u + 1], x.y, b1);
                b2 = fdot2f(whh[4 * u + 2], x.z, b2);
                b3 = fdot2f(whh[4 * u + 3], x.w, b3);
            }
        }
        {
            float a0 = 0, a1 = 0, a2 = 0, a3 = 0;
#pragma unroll
            for (int u = 0; u < 4; ++u) {
                uint4 x = ((const uint4*)rbuf)[(q << 2) + u];
                a0 = fdot2f(wfr[4 * u + 0], x.x, a0);
                a1 = fdot2f(wfr[4 * u + 1], x.y, a1);
                a2 = fdot2f(wfr[4 * u + 2], x.z, a2);
                a3 = fdot2f(wfr[4 * u + 3], x.w, a3);
            }
            float accf = quad_red((a0 + a1) + (a2 + a3));
            float kfc, kfd;
            unp2(kfb[cur][d >> 1], kfc, kfd);
            float fv = tanh_fast(accf + ((d & 1) ? kfd : kfc) + vbf);
            if (q == 0) ((u16*)fbuf)[d] = __builtin_bit_cast(u16, (f16)fv);
        }
        __syncthreads();                                     // B2
        // ===== P3: memrec we + lstm W_ih·ft dot (+park prefetch) ===========
        float g0 = vbsum, g1 = 0, g2 = 0, g3 = 0;
        {
            const uint4* f4 = (const uint4*)fbuf;
#pragma unroll
            for (int u = 0; u < 16; ++u) {
                uint4 x = f4[u];
                g0 = fdot2f(wih[4 * u + 0], x.x, g0);
                g1 = fdot2f(wih[4 * u + 1], x.y, g1);
                g2 = fdot2f(wih[4 * u + 2], x.z, g2);
                g3 = fdot2f(wih[4 * u + 3], x.w, g3);
            }
        }
        {
            float c0 = 0, c1 = 0, c2 = 0, c3 = 0;
#pragma unroll
            for (int u = 0; u < 4; ++u) {
                uint4 x = ((const uint4*)fbuf)[(q << 2) + u];
                c0 = fdot2f(waf[4 * u + 0], x.x, c0);
                c1 = fdot2f(waf[4 * u + 1], x.y, c1);
                c2 = fdot2f(waf[4 * u + 2], x.z, c2);
                c3 = fdot2f(waf[4 * u + 3], x.w, c3);
            }
            float accw = quad_red((c0 + c1) + (c2 + c3));
            float yac, yad;
            unp2(yab[cur][d >> 1], yac, yad);
            if (q == 0) ((u16*)wbuf)[d] =
                __builtin_bit_cast(u16, (f16)(accw + ((d & 1) ? yad : yac) + vba));
        }
        float gv = ((g0 + g1) + (g2 + g3)) + ((b0 + b1) + (b2 + b3));
        if (t + 1 < Sn && pu >= 0) {
            int nxt = cur ^ 1;
            if (pu < 32)      cwb[nxt][pu] = pfv;
            else if (pu < 96) kfb[nxt][pu - 32] = pfv;
            else              yab[nxt][pu - 96] = pfv;
        }
        __syncthreads();                                     // B3
        // ===== P4: memrec erase/add (weights from LDS) + mem update + lstm ==
        {
            float e0 = 0, e1 = 0, h0 = 0, h1 = 0;
#pragma unroll
            for (int u = 0; u < 4; ++u) {
                uint4 x  = ((const uint4*)wbuf)[(q << 2) + u];
                uint4 we4 = ((const uint4*)wewS)[u * 512 + tid];
                uint4 wd4 = ((const uint4*)wadwS)[u * 512 + tid];
                e0 = fdot2f(we4.x, x.x, e0);   h0 = fdot2f(wd4.x, x.x, h0);
                e1 = fdot2f(we4.y, x.y, e1);   h1 = fdot2f(wd4.y, x.y, h1);
                e0 = fdot2f(we4.z, x.z, e0);   h0 = fdot2f(wd4.z, x.z, h0);
                e1 = fdot2f(we4.w, x.w, e1);   h1 = fdot2f(wd4.w, x.w, h1);
            }
            float pe = quad_red(e0 + e1);
            float pa = quad_red(h0 + h1);
            float ev = sig_fast(pe + vbe);
            float av = tanh_fast(pa + vbad);
            // re-unpack cw for this t (cwb[cur] still valid: prefetch wrote nxt)
            uint4 cA = ((const uint4*)cwb[cur])[2 * q];
            uint4 cB = ((const uint4*)cwb[cur])[2 * q + 1];
            float lo, hi;
#define MUP(i0, i1, word) \
            unp2(word, lo, hi); \
            memv[i0] = fmaf(lo, fmaf(-ev, memv[i0], av), memv[i0]); \
            memv[i1] = fmaf(hi, fmaf(-ev, memv[i1], av), memv[i1]);
            MUP(0, 1, cA.x)  MUP(2, 3, cA.y)  MUP(4, 5, cA.z)  MUP(6, 7, cA.w)
            MUP(8, 9, cB.x)  MUP(10, 11, cB.y) MUP(12, 13, cB.z) MUP(14, 15, cB.w)
#undef MUP
        }
        // lstm gate exchange within quad + state update
        float gi = qdpp<0x00>(gv);
        float gf = qdpp<0x55>(gv);
        float gg = qdpp<0xAA>(gv);
        float go = qdpp<0xFF>(gv);
        float ig = sig_fast(gi), fg = sig_fast(gf);
        float gt = tanh_fast(gg), og = sig_fast(go);
        cx = fmaf(fg, cx, ig * gt);
        float hv = og * tanh_fast(cx);
        if (q == 0) ((u16*)HL)[(t + 1) * 128 + d] = __builtin_bit_cast(u16, (f16)hv);
    }
    __syncthreads();
    // ---- logits epilogue ----
    int w = tid >> 6, lane = tid & 63;
    for (int rr = w * 25; rr < w * 25 + 25; ++rr) {
        float acc = fdot2f(HL[(rr + 1) * 64 + lane], wpL[lane], 0.0f);
        for (int off = 32; off; off >>= 1) acc += __shfl_xor(acc, off);
        if (lane == 0) out[b * Sn + rr] = sig_fast(acc + bpL);
    }
}

// ---------------------------------------------------------------------------
extern "C" void kernel_launch(void* const* d_in, const int* in_sizes, int n_in,
                              void* d_out, int out_size, void* d_ws, size_t ws_size,
                              hipStream_t stream) {
    const int*   qseq = (const int*)d_in[0];
    const int*   cseq = (const int*)d_in[1];
    const float* Mk   = (const float*)d_in[2];
    const float* Mv0  = (const float*)d_in[3];
    const float* embc = (const float*)d_in[4];
    const float* embi = (const float*)d_in[5];
    const float* Wf   = (const float*)d_in[6];
    const float* bfv  = (const float*)d_in[7];
    const float* Wa   = (const float*)d_in[8];
    const float* bav  = (const float*)d_in[9];
    const float* We   = (const float*)d_in[10];
    const float* bev  = (const float*)d_in[11];
    const float* Wadd = (const float*)d_in[12];
    const float* badv = (const float*)d_in[13];
    const float* W_ih = (const float*)d_in[14];
    const float* W_hh = (const float*)d_in[15];
    const float* b_ih = (const float*)d_in[16];
    const float* b_hh = (const float*)d_in[17];
    const float* hx0  = (const float*)d_in[18];
    const float* cx0  = (const float*)d_in[19];
    const float* Wp   = (const float*)d_in[20];
    const float* bp   = (const float*)d_in[21];
    float* out = (float*)d_out;

    char* ws = (char*)d_ws;
    u16* cw16 = (u16*)ws;                              // 6,553,600 B
    ulonglong2* codes = (ulonglong2*)(ws + 6553600);   //   819,200 B
    int* prev = (int*)(ws + 7372800);                  //   204,800 B
    u16* kf16 = (u16*)(ws + 7577600);                  // 13,107,200 B
    u16* ya16 = (u16*)(ws + 20684800);                 // 13,107,200 B -> 33.8 MB

    phase0_kernel<<<(Bn * Sn) / 8, 512, 0, stream>>>(qseq, Mk, embc, cw16, codes);
    pre_kernel<<<(Bn * Sn) / 8, 512, 0, stream>>>(Wf, embc, qseq, cseq, 0, kf16);
    pre_kernel<<<(Bn * Sn) / 8, 512, 0, stream>>>(Wa, embi, qseq, cseq, 1, ya16);
    match_kernel<<<Bn, 256, 0, stream>>>(codes, prev);
    fused_kernel<<<Bn, 512, 0, stream>>>(Mv0, Wf, bfv, Wa, bav, We, bev, Wadd, badv,
                                         W_ih, W_hh, b_ih, b_hh, hx0, cx0, Wp, bp,
                                         cw16, kf16, ya16, prev, out);
}

// Round 6
// 5241.215 us; speedup vs baseline: 1.0016x; 1.0016x over previous
//
#include <hip/hip_runtime.h>

typedef unsigned int u32;
typedef unsigned short u16;
typedef unsigned long long u64;
typedef _Float16 f16;
typedef _Float16 f16x2 __attribute__((ext_vector_type(2)));

#define Bn 256
#define Sn 200
#define Dn 128
#define Mn 64
#define NQn 5000

__device__ __forceinline__ float fdot2f(u32 w, u32 x, float acc) {
#if __has_builtin(__builtin_amdgcn_fdot2)
    return __builtin_amdgcn_fdot2(__builtin_bit_cast(f16x2, w),
                                  __builtin_bit_cast(f16x2, x), acc, false);
#else
    f16x2 a = __builtin_bit_cast(f16x2, w);
    f16x2 b = __builtin_bit_cast(f16x2, x);
    return acc + (float)a[0] * (float)b[0] + (float)a[1] * (float)b[1];
#endif
}

__device__ __forceinline__ u32 packh2(float a, float b) {
    u16 ua = __builtin_bit_cast(u16, (f16)a);
    u16 ub = __builtin_bit_cast(u16, (f16)b);
    return (u32)ua | ((u32)ub << 16);
}

__device__ __forceinline__ void unp2(u32 v, float& lo, float& hi) {
    lo = (float)__builtin_bit_cast(f16, (u16)(v & 0xffff));
    hi = (float)__builtin_bit_cast(f16, (u16)(v >> 16));
}

__device__ __forceinline__ float fexp2f(float x) {
#if __has_builtin(__builtin_amdgcn_exp2f)
    return __builtin_amdgcn_exp2f(x);
#else
    return exp2f(x);
#endif
}
__device__ __forceinline__ float frcpf(float x) {
#if __has_builtin(__builtin_amdgcn_rcpf)
    return __builtin_amdgcn_rcpf(x);
#else
    return 1.0f / x;
#endif
}
__device__ __forceinline__ float sig_fast(float x)  { return frcpf(1.0f + fexp2f(-1.44269504f * x)); }
__device__ __forceinline__ float tanh_fast(float x) { return fmaf(-2.0f, frcpf(1.0f + fexp2f(2.88539008f * x)), 1.0f); }

// ---- DPP quad helpers -----------------------------------------------------
template<int CTRL>
__device__ __forceinline__ float qdpp(float x) {
    return __builtin_bit_cast(float, __builtin_amdgcn_update_dpp(
        0, __builtin_bit_cast(int, x), CTRL, 0xF, 0xF, true));
}
__device__ __forceinline__ float quad_red(float x) {
    x += qdpp<0xB1>(x);   // quad_perm [1,0,3,2]
    x += qdpp<0x4E>(x);   // quad_perm [2,3,0,1]
    return x;
}

// ---------------------------------------------------------------------------
// Kernel A: cw = softmax(k @ Mk^T) fp32 + iv-code ballots. (R2 shape)
// ---------------------------------------------------------------------------
__global__ __launch_bounds__(512) void phase0_kernel(
    const int* __restrict__ qseq,
    const float* __restrict__ Mk, const float* __restrict__ embc,
    u16* __restrict__ cw16, ulonglong2* __restrict__ codes)
{
    __shared__ float MkT[Dn * 65];
    __shared__ float kb[8][Dn];
    int tid = threadIdx.x;
    for (int idx = tid; idx < Mn * Dn; idx += 512) {
        int m = idx >> 7, d = idx & 127;
        MkT[d * 65 + m] = Mk[idx];
    }
    __syncthreads();
    int w = tid >> 6, lane = tid & 63;
    int item = blockIdx.x * 8 + w;
    int qq = qseq[item];
    kb[w][lane]      = embc[qq * Dn + lane];
    kb[w][lane + 64] = embc[qq * Dn + lane + 64];
    __syncthreads();
    float acc = 0.0f;
    const float* kw = kb[w];
#pragma unroll 8
    for (int d = 0; d < Dn; ++d)
        acc = fmaf(MkT[d * 65 + lane], kw[d], acc);
    float mx = acc;
    for (int off = 32; off; off >>= 1) mx = fmaxf(mx, __shfl_xor(mx, off));
    float e = expf(acc - mx);
    float sm = e;
    for (int off = 32; off; off >>= 1) sm += __shfl_xor(sm, off);
    float cw = e / sm;
    cw16[item * Mn + lane] = __builtin_bit_cast(u16, (f16)cw);
    float t1 = (cw - 0.01f) / (0.05f - 0.01f);
    float t2 = (0.1f - cw) / (0.1f - 0.05f);
    float tri = fmaxf(fminf(t1, t2), 0.0f);
    int iv = (tri >= 0.6f) ? 2 : ((tri >= 0.1f) ? 1 : 0);
    u64 b1 = __ballot(iv >= 1);
    u64 b2 = __ballot(iv == 2);
    if (lane == 0) { codes[item].x = b1; codes[item].y = b2; }
}

// ---------------------------------------------------------------------------
// Kernel B: prev_t match. (unchanged)
// ---------------------------------------------------------------------------
__global__ __launch_bounds__(256) void match_kernel(
    const ulonglong2* __restrict__ codes, int* __restrict__ prev)
{
    __shared__ u64 clo[Sn], chi[Sn];
    int b = blockIdx.x, tid = threadIdx.x;
    if (tid < Sn) { ulonglong2 c = codes[b * Sn + tid]; clo[tid] = c.x; chi[tid] = c.y; }
    __syncthreads();
    if (tid < Sn) {
        u64 mylo = clo[tid], myhi = chi[tid];
        int best = -1;
        for (int j = 0; j < tid; ++j)
            if (clo[j] == mylo && chi[j] == myhi) best = j;
        prev[b * Sn + tid] = best;
    }
}

// ---------------------------------------------------------------------------
// Kernel P: hoisted recurrence-independent matvecs. (R2 shape)
// ---------------------------------------------------------------------------
__global__ __launch_bounds__(512) void pre_kernel(
    const float* __restrict__ W, const float* __restrict__ emb,
    const int* __restrict__ qseq, const int* __restrict__ cseq, int mode,
    u16* __restrict__ outp)
{
    __shared__ u32 wL[128 * 65];
    __shared__ u32 vb[8][64];
    int tid = threadIdx.x;
    for (int idx = tid; idx < 128 * 64; idx += 512) {
        int dd = idx >> 6, jj = idx & 63;
        const float2 wv = *(const float2*)(W + dd * 256 + 128 + 2 * jj);
        wL[dd * 65 + jj] = packh2(wv.x, wv.y);
    }
    int w = tid >> 6, lane = tid & 63;
    int item = blockIdx.x * 8 + w;
    int row = qseq[item];
    if (mode) row += NQn * cseq[item];
    {
        const float2 kv = *(const float2*)(emb + row * Dn + 2 * lane);
        vb[w][lane] = packh2(kv.x, kv.y);
    }
    __syncthreads();
    const u32* w0 = wL + lane * 65;
    const u32* w1 = wL + (64 + lane) * 65;
    const u32* x  = vb[w];
    float a0 = 0, a1 = 0, b0 = 0, b1 = 0;
#pragma unroll
    for (int jj = 0; jj < 64; jj += 2) {
        a0 = fdot2f(w0[jj],     x[jj],     a0);
        a1 = fdot2f(w0[jj + 1], x[jj + 1], a1);
        b0 = fdot2f(w1[jj],     x[jj],     b0);
        b1 = fdot2f(w1[jj + 1], x[jj + 1], b1);
    }
    outp[item * Dn + lane]      = __builtin_bit_cast(u16, (f16)(a0 + a1));
    outp[item * Dn + 64 + lane] = __builtin_bit_cast(u16, (f16)(b0 + b1));
}

// ---------------------------------------------------------------------------
// Kernel F: FUSED memrec + hop-LSTM (v4).
//  ONLY change vs v3: explicit LLVM attrs amdgpu_flat_work_group_size(512,512)
//  + amdgpu_waves_per_eu(2,2). Rationale: VGPR_Count was pinned at 128 across
//  __launch_bounds__(512,2)/(512,1) — i.e. launch_bounds never reached the
//  backend's VGPR-budget decision, which defaulted to the 1024-thread/4-waves-
//  per-EU assumption (512-reg pool / 4 = 128). Forcing exactly 2 waves/EU
//  gives the 256-VGPR budget the ~176-reg persistent weight set needs.
//  1 block/CU is already forced by 120 KB LDS + grid == #CUs.
// ---------------------------------------------------------------------------
__global__
__attribute__((amdgpu_flat_work_group_size(512, 512), amdgpu_waves_per_eu(2, 2)))
void fused_kernel(
    const float* __restrict__ Mv0,
    const float* __restrict__ Wf, const float* __restrict__ bfv,
    const float* __restrict__ Wa, const float* __restrict__ bav,
    const float* __restrict__ We, const float* __restrict__ bev,
    const float* __restrict__ Wadd, const float* __restrict__ badv,
    const float* __restrict__ W_ih, const float* __restrict__ W_hh,
    const float* __restrict__ b_ih, const float* __restrict__ b_hh,
    const float* __restrict__ hx0, const float* __restrict__ cx0,
    const float* __restrict__ Wp, const float* __restrict__ bp,
    const u16* __restrict__ cw16, const u16* __restrict__ kf16,
    const u16* __restrict__ ya16, const int* __restrict__ prev,
    float* __restrict__ out)
{
    __shared__ __align__(16) u32 HL[(Sn + 1) * 64];   // 51.4 KB
    __shared__ __align__(16) u32 wewS[4 * 512 * 4];   // 32 KB, consumer-ordered
    __shared__ __align__(16) u32 wadwS[4 * 512 * 4];  // 32 KB
    __shared__ __align__(16) u32 cwb[2][32];
    __shared__ __align__(16) u32 kfb[2][64];
    __shared__ __align__(16) u32 yab[2][64];
    __shared__ __align__(16) u32 rbuf[64], fbuf[64], wbuf[64];
    __shared__ int prevL[Sn];
    __shared__ u32 wpL[64];
    __shared__ float bpL;

    int tid = threadIdx.x, b = blockIdx.x;
    int d = tid >> 2, q = tid & 3;

    // ---- register-resident weights: Wf_read-half, Wa_f-half ----
    u32 wfr[16], waf[16];
    {
        const float2* pf = (const float2*)(Wf + d * 256 + q * 32);
        const float2* pa = (const float2*)(Wa + d * 256 + q * 32);
#pragma unroll
        for (int i = 0; i < 16; ++i) {
            float2 a;
            a = pf[i]; wfr[i] = packh2(a.x, a.y);
            a = pa[i]; waf[i] = packh2(a.x, a.y);
        }
    }
    // ---- We/Wadd -> LDS, consumer order (chunk u, thread tid) ----
    {
        const float2* pe = (const float2*)(We + d * 128 + q * 32);
        const float2* pd = (const float2*)(Wadd + d * 128 + q * 32);
#pragma unroll
        for (int u = 0; u < 4; ++u) {
#pragma unroll
            for (int j = 0; j < 4; ++j) {
                float2 a;
                a = pe[4 * u + j]; wewS[(u * 512 + tid) * 4 + j]  = packh2(a.x, a.y);
                a = pd[4 * u + j]; wadwS[(u * 512 + tid) * 4 + j] = packh2(a.x, a.y);
            }
        }
    }
    int r = q * 128 + d;                     // lstm gate row (i,f,g,o)
    u32 wih[64], whh[64];
    {
        const float2* wi2 = (const float2*)(W_ih + r * Dn);
        const float2* wh2 = (const float2*)(W_hh + r * Dn);
#pragma unroll
        for (int i = 0; i < 64; ++i) {
            float2 a;
            a = wi2[i]; wih[i] = packh2(a.x, a.y);
            a = wh2[i]; whh[i] = packh2(a.x, a.y);
        }
    }
    float memv[16];
#pragma unroll
    for (int i = 0; i < 16; ++i) memv[i] = Mv0[(q * 16 + i) * Dn + d];
    float vbf = bfv[d], vba = bav[d], vbe = bev[d], vbad = badv[d];
    float vbsum = b_ih[r] + b_hh[r];
    float cx = cx0[d];

    if (tid < 64) {
        HL[tid]  = packh2(hx0[2 * tid], hx0[2 * tid + 1]);
        wpL[tid] = packh2(Wp[2 * tid], Wp[2 * tid + 1]);
    }
    { int u = tid - 64;  if (u >= 0 && u < 32) cwb[0][u] = ((const u32*)cw16)[(b * Sn) * 32 + u]; }
    { int u = tid - 96;  if (u >= 0 && u < 64) kfb[0][u] = ((const u32*)kf16)[(size_t)(b * Sn) * 64 + u]; }
    { int u = tid - 160; if (u >= 0 && u < 64) yab[0][u] = ((const u32*)ya16)[(size_t)(b * Sn) * 64 + u]; }
    if (tid < Sn) prevL[tid] = prev[b * Sn + tid];
    if (tid == 0) bpL = bp[0];
    __syncthreads();

    int pu = tid - 352;          // prefetch role: 0..159 (32 cw + 64 kf + 64 ya)
    u32 pfv = 0;

    for (int t = 0; t < Sn; ++t) {
        int cur = t & 1;
        // ===== P1: memrec read partial (+issue t+1 prefetch loads) =========
        {
            float lo, hi;
            float p0 = 0, p1 = 0, p2 = 0, p3 = 0;
            uint4 cA = ((const uint4*)cwb[cur])[2 * q];
            uint4 cB = ((const uint4*)cwb[cur])[2 * q + 1];
            unp2(cA.x, lo, hi); p0 = fmaf(lo, memv[0], p0); p1 = fmaf(hi, memv[1], p1);
            unp2(cA.y, lo, hi); p2 = fmaf(lo, memv[2], p2); p3 = fmaf(hi, memv[3], p3);
            unp2(cA.z, lo, hi); p0 = fmaf(lo, memv[4], p0); p1 = fmaf(hi, memv[5], p1);
            unp2(cA.w, lo, hi); p2 = fmaf(lo, memv[6], p2); p3 = fmaf(hi, memv[7], p3);
            unp2(cB.x, lo, hi); p0 = fmaf(lo, memv[8], p0); p1 = fmaf(hi, memv[9], p1);
            unp2(cB.y, lo, hi); p2 = fmaf(lo, memv[10], p2); p3 = fmaf(hi, memv[11], p3);
            unp2(cB.z, lo, hi); p0 = fmaf(lo, memv[12], p0); p1 = fmaf(hi, memv[13], p1);
            unp2(cB.w, lo, hi); p2 = fmaf(lo, memv[14], p2); p3 = fmaf(hi, memv[15], p3);
            float pr = quad_red((p0 + p1) + (p2 + p3));
            if (q == 0) ((u16*)rbuf)[d] = __builtin_bit_cast(u16, (f16)pr);
        }
        if (t + 1 < Sn && pu >= 0) {
            if (pu < 32)      pfv = ((const u32*)cw16)[(b * Sn + t + 1) * 32 + pu];
            else if (pu < 96) pfv = ((const u32*)kf16)[(size_t)(b * Sn + t + 1) * 64 + (pu - 32)];
            else              pfv = ((const u32*)ya16)[(size_t)(b * Sn + t + 1) * 64 + (pu - 96)];
        }
        int pv = prevL[t];
        int hrow = (pv >= 0) ? (pv + 1) : t;
        __syncthreads();                                     // B1
        // ===== P2: memrec f  +  lstm W_hh·h dot ============================
        float b0 = 0, b1 = 0, b2 = 0, b3 = 0;
        {
            const uint4* h4 = (const uint4*)(HL + hrow * 64);
#pragma unroll
            for (int u = 0; u < 16; ++u) {
                uint4 x = h4[u];
                b0 = fdot2f(whh[4 * u + 0], x.x, b0);
                b1 = fdot2f(whh[4 * u + 1], x.y, b1);
                b2 = fdot2f(whh[4 * u + 2], x.z, b2);
                b3 = fdot2f(whh[4 * u + 3], x.w, b3);
            }
        }
        {
            float a0 = 0, a1 = 0, a2 = 0, a3 = 0;
#pragma unroll
            for (int u = 0; u < 4; ++u) {
                uint4 x = ((const uint4*)rbuf)[(q << 2) + u];
                a0 = fdot2f(wfr[4 * u + 0], x.x, a0);
                a1 = fdot2f(wfr[4 * u + 1], x.y, a1);
                a2 = fdot2f(wfr[4 * u + 2], x.z, a2);
                a3 = fdot2f(wfr[4 * u + 3], x.w, a3);
            }
            float accf = quad_red((a0 + a1) + (a2 + a3));
            float kfc, kfd;
            unp2(kfb[cur][d >> 1], kfc, kfd);
            float fv = tanh_fast(accf + ((d & 1) ? kfd : kfc) + vbf);
            if (q == 0) ((u16*)fbuf)[d] = __builtin_bit_cast(u16, (f16)fv);
        }
        __syncthreads();                                     // B2
        // ===== P3: memrec we + lstm W_ih·ft dot (+park prefetch) ===========
        float g0 = vbsum, g1 = 0, g2 = 0, g3 = 0;
        {
            const uint4* f4 = (const uint4*)fbuf;
#pragma unroll
            for (int u = 0; u < 16; ++u) {
                uint4 x = f4[u];
                g0 = fdot2f(wih[4 * u + 0], x.x, g0);
                g1 = fdot2f(wih[4 * u + 1], x.y, g1);
                g2 = fdot2f(wih[4 * u + 2], x.z, g2);
                g3 = fdot2f(wih[4 * u + 3], x.w, g3);
            }
        }
        {
            float c0 = 0, c1 = 0, c2 = 0, c3 = 0;
#pragma unroll
            for (int u = 0; u < 4; ++u) {
                uint4 x = ((const uint4*)fbuf)[(q << 2) + u];
                c0 = fdot2f(waf[4 * u + 0], x.x, c0);
                c1 = fdot2f(waf[4 * u + 1], x.y, c1);
                c2 = fdot2f(waf[4 * u + 2], x.z, c2);
                c3 = fdot2f(waf[4 * u + 3], x.w, c3);
            }
            float accw = quad_red((c0 + c1) + (c2 + c3));
            float yac, yad;
            unp2(yab[cur][d >> 1], yac, yad);
            if (q == 0) ((u16*)wbuf)[d] =
                __builtin_bit_cast(u16, (f16)(accw + ((d & 1) ? yad : yac) + vba));
        }
        float gv = ((g0 + g1) + (g2 + g3)) + ((b0 + b1) + (b2 + b3));
        if (t + 1 < Sn && pu >= 0) {
            int nxt = cur ^ 1;
            if (pu < 32)      cwb[nxt][pu] = pfv;
            else if (pu < 96) kfb[nxt][pu - 32] = pfv;
            else              yab[nxt][pu - 96] = pfv;
        }
        __syncthreads();                                     // B3
        // ===== P4: memrec erase/add (weights from LDS) + mem update + lstm ==
        {
            float e0 = 0, e1 = 0, h0 = 0, h1 = 0;
#pragma unroll
            for (int u = 0; u < 4; ++u) {
                uint4 x  = ((const uint4*)wbuf)[(q << 2) + u];
                uint4 we4 = ((const uint4*)wewS)[u * 512 + tid];
                uint4 wd4 = ((const uint4*)wadwS)[u * 512 + tid];
                e0 = fdot2f(we4.x, x.x, e0);   h0 = fdot2f(wd4.x, x.x, h0);
                e1 = fdot2f(we4.y, x.y, e1);   h1 = fdot2f(wd4.y, x.y, h1);
                e0 = fdot2f(we4.z, x.z, e0);   h0 = fdot2f(wd4.z, x.z, h0);
                e1 = fdot2f(we4.w, x.w, e1);   h1 = fdot2f(wd4.w, x.w, h1);
            }
            float pe = quad_red(e0 + e1);
            float pa = quad_red(h0 + h1);
            float ev = sig_fast(pe + vbe);
            float av = tanh_fast(pa + vbad);
            // re-unpack cw for this t (cwb[cur] still valid: prefetch wrote nxt)
            uint4 cA = ((const uint4*)cwb[cur])[2 * q];
            uint4 cB = ((const uint4*)cwb[cur])[2 * q + 1];
            float lo, hi;
#define MUP(i0, i1, word) \
            unp2(word, lo, hi); \
            memv[i0] = fmaf(lo, fmaf(-ev, memv[i0], av), memv[i0]); \
            memv[i1] = fmaf(hi, fmaf(-ev, memv[i1], av), memv[i1]);
            MUP(0, 1, cA.x)  MUP(2, 3, cA.y)  MUP(4, 5, cA.z)  MUP(6, 7, cA.w)
            MUP(8, 9, cB.x)  MUP(10, 11, cB.y) MUP(12, 13, cB.z) MUP(14, 15, cB.w)
#undef MUP
        }
        // lstm gate exchange within quad + state update
        float gi = qdpp<0x00>(gv);
        float gf = qdpp<0x55>(gv);
        float gg = qdpp<0xAA>(gv);
        float go = qdpp<0xFF>(gv);
        float ig = sig_fast(gi), fg = sig_fast(gf);
        float gt = tanh_fast(gg), og = sig_fast(go);
        cx = fmaf(fg, cx, ig * gt);
        float hv = og * tanh_fast(cx);
        if (q == 0) ((u16*)HL)[(t + 1) * 128 + d] = __builtin_bit_cast(u16, (f16)hv);
    }
    __syncthreads();
    // ---- logits epilogue ----
    int w = tid >> 6, lane = tid & 63;
    for (int rr = w * 25; rr < w * 25 + 25; ++rr) {
        float acc = fdot2f(HL[(rr + 1) * 64 + lane], wpL[lane], 0.0f);
        for (int off = 32; off; off >>= 1) acc += __shfl_xor(acc, off);
        if (lane == 0) out[b * Sn + rr] = sig_fast(acc + bpL);
    }
}

// ---------------------------------------------------------------------------
extern "C" void kernel_launch(void* const* d_in, const int* in_sizes, int n_in,
                              void* d_out, int out_size, void* d_ws, size_t ws_size,
                              hipStream_t stream) {
    const int*   qseq = (const int*)d_in[0];
    const int*   cseq = (const int*)d_in[1];
    const float* Mk   = (const float*)d_in[2];
    const float* Mv0  = (const float*)d_in[3];
    const float* embc = (const float*)d_in[4];
    const float* embi = (const float*)d_in[5];
    const float* Wf   = (const float*)d_in[6];
    const float* bfv  = (const float*)d_in[7];
    const float* Wa   = (const float*)d_in[8];
    const float* bav  = (const float*)d_in[9];
    const float* We   = (const float*)d_in[10];
    const float* bev  = (const float*)d_in[11];
    const float* Wadd = (const float*)d_in[12];
    const float* badv = (const float*)d_in[13];
    const float* W_ih = (const float*)d_in[14];
    const float* W_hh = (const float*)d_in[15];
    const float* b_ih = (const float*)d_in[16];
    const float* b_hh = (const float*)d_in[17];
    const float* hx0  = (const float*)d_in[18];
    const float* cx0  = (const float*)d_in[19];
    const float* Wp   = (const float*)d_in[20];
    const float* bp   = (const float*)d_in[21];
    float* out = (float*)d_out;

    char* ws = (char*)d_ws;
    u16* cw16 = (u16*)ws;                              // 6,553,600 B
    ulonglong2* codes = (ulonglong2*)(ws + 6553600);   //   819,200 B
    int* prev = (int*)(ws + 7372800);                  //   204,800 B
    u16* kf16 = (u16*)(ws + 7577600);                  // 13,107,200 B
    u16* ya16 = (u16*)(ws + 20684800);                 // 13,107,200 B -> 33.8 MB

    phase0_kernel<<<(Bn * Sn) / 8, 512, 0, stream>>>(qseq, Mk, embc, cw16, codes);
    pre_kernel<<<(Bn * Sn) / 8, 512, 0, stream>>>(Wf, embc, qseq, cseq, 0, kf16);
    pre_kernel<<<(Bn * Sn) / 8, 512, 0, stream>>>(Wa, embi, qseq, cseq, 1, ya16);
    match_kernel<<<Bn, 256, 0, stream>>>(codes, prev);
    fused_kernel<<<Bn, 512, 0, stream>>>(Mv0, Wf, bfv, Wa, bav, We, bev, Wadd, badv,
                                         W_ih, W_hh, b_ih, b_hh, hx0, cx0, Wp, bp,
                                         cw16, kf16, ya16, prev, out);
}

// Round 7
// 1517.544 us; speedup vs baseline: 3.4593x; 3.4537x over previous
//
#include <hip/hip_runtime.h>

typedef unsigned int u32;
typedef unsigned short u16;
typedef unsigned long long u64;
typedef _Float16 f16;
typedef _Float16 f16x2 __attribute__((ext_vector_type(2)));

#define Bn 256
#define Sn 200
#define Dn 128
#define Mn 64
#define NQn 5000

__device__ __forceinline__ float fdot2f(u32 w, u32 x, float acc) {
#if __has_builtin(__builtin_amdgcn_fdot2)
    return __builtin_amdgcn_fdot2(__builtin_bit_cast(f16x2, w),
                                  __builtin_bit_cast(f16x2, x), acc, false);
#else
    f16x2 a = __builtin_bit_cast(f16x2, w);
    f16x2 b = __builtin_bit_cast(f16x2, x);
    return acc + (float)a[0] * (float)b[0] + (float)a[1] * (float)b[1];
#endif
}

__device__ __forceinline__ u32 packh2(float a, float b) {
    u16 ua = __builtin_bit_cast(u16, (f16)a);
    u16 ub = __builtin_bit_cast(u16, (f16)b);
    return (u32)ua | ((u32)ub << 16);
}

__device__ __forceinline__ void unp2(u32 v, float& lo, float& hi) {
    lo = (float)__builtin_bit_cast(f16, (u16)(v & 0xffff));
    hi = (float)__builtin_bit_cast(f16, (u16)(v >> 16));
}

__device__ __forceinline__ float fexp2f(float x) {
#if __has_builtin(__builtin_amdgcn_exp2f)
    return __builtin_amdgcn_exp2f(x);
#else
    return exp2f(x);
#endif
}
__device__ __forceinline__ float frcpf(float x) {
#if __has_builtin(__builtin_amdgcn_rcpf)
    return __builtin_amdgcn_rcpf(x);
#else
    return 1.0f / x;
#endif
}
__device__ __forceinline__ float sig_fast(float x)  { return frcpf(1.0f + fexp2f(-1.44269504f * x)); }
__device__ __forceinline__ float tanh_fast(float x) { return fmaf(-2.0f, frcpf(1.0f + fexp2f(2.88539008f * x)), 1.0f); }

// ---- DPP helpers ----------------------------------------------------------
template<int CTRL>
__device__ __forceinline__ float qdpp(float x) {
    return __builtin_bit_cast(float, __builtin_amdgcn_update_dpp(
        0, __builtin_bit_cast(int, x), CTRL, 0xF, 0xF, true));
}
// sum over 8-lane oct (lanes dd*8 .. dd*8+7), all lanes get the total
__device__ __forceinline__ float oct_red(float x) {
    x += qdpp<0xB1>(x);          // xor 1 (quad_perm [1,0,3,2])
    x += qdpp<0x4E>(x);          // xor 2 (quad_perm [2,3,0,1])
    x += __shfl_xor(x, 4);       // xor 4 (cross-quad within oct)
    return x;
}

// ---------------------------------------------------------------------------
// Kernel A: cw = softmax(k @ Mk^T) fp32 + iv-code ballots. (R2 shape)
// ---------------------------------------------------------------------------
__global__ __launch_bounds__(512) void phase0_kernel(
    const int* __restrict__ qseq,
    const float* __restrict__ Mk, const float* __restrict__ embc,
    u16* __restrict__ cw16, ulonglong2* __restrict__ codes)
{
    __shared__ float MkT[Dn * 65];
    __shared__ float kb[8][Dn];
    int tid = threadIdx.x;
    for (int idx = tid; idx < Mn * Dn; idx += 512) {
        int m = idx >> 7, d = idx & 127;
        MkT[d * 65 + m] = Mk[idx];
    }
    __syncthreads();
    int w = tid >> 6, lane = tid & 63;
    int item = blockIdx.x * 8 + w;
    int qq = qseq[item];
    kb[w][lane]      = embc[qq * Dn + lane];
    kb[w][lane + 64] = embc[qq * Dn + lane + 64];
    __syncthreads();
    float acc = 0.0f;
    const float* kw = kb[w];
#pragma unroll 8
    for (int d = 0; d < Dn; ++d)
        acc = fmaf(MkT[d * 65 + lane], kw[d], acc);
    float mx = acc;
    for (int off = 32; off; off >>= 1) mx = fmaxf(mx, __shfl_xor(mx, off));
    float e = expf(acc - mx);
    float sm = e;
    for (int off = 32; off; off >>= 1) sm += __shfl_xor(sm, off);
    float cw = e / sm;
    cw16[item * Mn + lane] = __builtin_bit_cast(u16, (f16)cw);
    float t1 = (cw - 0.01f) / (0.05f - 0.01f);
    float t2 = (0.1f - cw) / (0.1f - 0.05f);
    float tri = fmaxf(fminf(t1, t2), 0.0f);
    int iv = (tri >= 0.6f) ? 2 : ((tri >= 0.1f) ? 1 : 0);
    u64 b1 = __ballot(iv >= 1);
    u64 b2 = __ballot(iv == 2);
    if (lane == 0) { codes[item].x = b1; codes[item].y = b2; }
}

// ---------------------------------------------------------------------------
// Kernel B: prev_t match. (unchanged)
// ---------------------------------------------------------------------------
__global__ __launch_bounds__(256) void match_kernel(
    const ulonglong2* __restrict__ codes, int* __restrict__ prev)
{
    __shared__ u64 clo[Sn], chi[Sn];
    int b = blockIdx.x, tid = threadIdx.x;
    if (tid < Sn) { ulonglong2 c = codes[b * Sn + tid]; clo[tid] = c.x; chi[tid] = c.y; }
    __syncthreads();
    if (tid < Sn) {
        u64 mylo = clo[tid], myhi = chi[tid];
        int best = -1;
        for (int j = 0; j < tid; ++j)
            if (clo[j] == mylo && chi[j] == myhi) best = j;
        prev[b * Sn + tid] = best;
    }
}

// ---------------------------------------------------------------------------
// Kernel P: hoisted recurrence-independent matvecs. (R2 shape)
// ---------------------------------------------------------------------------
__global__ __launch_bounds__(512) void pre_kernel(
    const float* __restrict__ W, const float* __restrict__ emb,
    const int* __restrict__ qseq, const int* __restrict__ cseq, int mode,
    u16* __restrict__ outp)
{
    __shared__ u32 wL[128 * 65];
    __shared__ u32 vb[8][64];
    int tid = threadIdx.x;
    for (int idx = tid; idx < 128 * 64; idx += 512) {
        int dd = idx >> 6, jj = idx & 63;
        const float2 wv = *(const float2*)(W + dd * 256 + 128 + 2 * jj);
        wL[dd * 65 + jj] = packh2(wv.x, wv.y);
    }
    int w = tid >> 6, lane = tid & 63;
    int item = blockIdx.x * 8 + w;
    int row = qseq[item];
    if (mode) row += NQn * cseq[item];
    {
        const float2 kv = *(const float2*)(emb + row * Dn + 2 * lane);
        vb[w][lane] = packh2(kv.x, kv.y);
    }
    __syncthreads();
    const u32* w0 = wL + lane * 65;
    const u32* w1 = wL + (64 + lane) * 65;
    const u32* x  = vb[w];
    float a0 = 0, a1 = 0, b0 = 0, b1 = 0;
#pragma unroll
    for (int jj = 0; jj < 64; jj += 2) {
        a0 = fdot2f(w0[jj],     x[jj],     a0);
        a1 = fdot2f(w0[jj + 1], x[jj + 1], a1);
        b0 = fdot2f(w1[jj],     x[jj],     b0);
        b1 = fdot2f(w1[jj + 1], x[jj + 1], b1);
    }
    outp[item * Dn + lane]      = __builtin_bit_cast(u16, (f16)(a0 + a1));
    outp[item * Dn + 64 + lane] = __builtin_bit_cast(u16, (f16)(b0 + b1));
}

// ---------------------------------------------------------------------------
// Kernel F: FUSED memrec + hop-LSTM (v5) — 1024 threads, fits 128-VGPR budget.
//  The compiler pins this kernel's VGPR budget at 128 regardless of
//  launch_bounds/attrs (R3-R6: VGPR_Count==128 + GBs of scratch FETCH), so the
//  design now fits it: 1024 thr/block, per-thread state halved.
//   memrec: dd=tid>>3, o=tid&7 slice of 16 cols. regs: wfr[8], memv[8].
//           Wa_f/We/Wadd in LDS consumer-ordered. oct reduction (2 DPP + xor4).
//   lstm:   row r=g*128+dd (g=(tid>>1)&3), half=tid&1 half-row.
//           regs: wih[32], whh[32]. pair-reduce DPP xor1; gate gather via
//           3 in-oct shfls; lanes g==0 carry cx.
//  Persistent regs ~86, peak ~115 < 128 -> no spill. 3 barriers/step.
// ---------------------------------------------------------------------------
__global__ __launch_bounds__(1024) void fused_kernel(
    const float* __restrict__ Mv0,
    const float* __restrict__ Wf, const float* __restrict__ bfv,
    const float* __restrict__ Wa, const float* __restrict__ bav,
    const float* __restrict__ We, const float* __restrict__ bev,
    const float* __restrict__ Wadd, const float* __restrict__ badv,
    const float* __restrict__ W_ih, const float* __restrict__ W_hh,
    const float* __restrict__ b_ih, const float* __restrict__ b_hh,
    const float* __restrict__ hx0, const float* __restrict__ cx0,
    const float* __restrict__ Wp, const float* __restrict__ bp,
    const u16* __restrict__ cw16, const u16* __restrict__ kf16,
    const u16* __restrict__ ya16, const int* __restrict__ prev,
    float* __restrict__ out)
{
    __shared__ __align__(16) u32 HL[(Sn + 1) * 64];   // 51.4 KB
    __shared__ __align__(16) u32 wafS[2 * 1024 * 4];  // 32 KB (Wa f-half)
    __shared__ __align__(16) u32 wewS[2 * 1024 * 4];  // 32 KB
    __shared__ __align__(16) u32 wadwS[2 * 1024 * 4]; // 32 KB
    __shared__ __align__(16) u32 cwb[2][32];
    __shared__ __align__(16) u32 kfb[2][64];
    __shared__ __align__(16) u32 yab[2][64];
    __shared__ __align__(16) u32 rbuf[64], fbuf[64], wbuf[64];
    __shared__ int prevL[Sn];
    __shared__ u32 wpL[64];
    __shared__ float bpL;

    int tid = threadIdx.x, b = blockIdx.x;
    int dd = tid >> 3, o = tid & 7;        // memrec slice
    int g = (tid >> 1) & 3, half = tid & 1; // lstm role
    int r = g * 128 + dd;                   // lstm gate row (i,f,g,o)

    // ---- register-resident: Wf read-half slice (16 f16) ----
    u32 wfr[8];
    {
        const float2* pf = (const float2*)(Wf + dd * 256 + o * 16);
#pragma unroll
        for (int i = 0; i < 8; ++i) { float2 a = pf[i]; wfr[i] = packh2(a.x, a.y); }
    }
    // ---- Wa_f / We / Wadd -> LDS, consumer order (2 uint4 chunks/thread) ----
    {
        const float2* pa = (const float2*)(Wa + dd * 256 + o * 16);
        const float2* pe = (const float2*)(We + dd * 128 + o * 16);
        const float2* pd = (const float2*)(Wadd + dd * 128 + o * 16);
#pragma unroll
        for (int u = 0; u < 2; ++u) {
#pragma unroll
            for (int j = 0; j < 4; ++j) {
                float2 a;
                a = pa[u * 4 + j]; wafS[(u * 1024 + tid) * 4 + j]  = packh2(a.x, a.y);
                a = pe[u * 4 + j]; wewS[(u * 1024 + tid) * 4 + j]  = packh2(a.x, a.y);
                a = pd[u * 4 + j]; wadwS[(u * 1024 + tid) * 4 + j] = packh2(a.x, a.y);
            }
        }
    }
    // ---- lstm half-row weights (64 f16 each) ----
    u32 wih[32], whh[32];
    {
        const float2* wi2 = (const float2*)(W_ih + r * Dn + half * 64);
        const float2* wh2 = (const float2*)(W_hh + r * Dn + half * 64);
#pragma unroll
        for (int i = 0; i < 32; ++i) {
            float2 a;
            a = wi2[i]; wih[i] = packh2(a.x, a.y);
            a = wh2[i]; whh[i] = packh2(a.x, a.y);
        }
    }
    float memv[8];
#pragma unroll
    for (int i = 0; i < 8; ++i) memv[i] = Mv0[(o * 8 + i) * Dn + dd];
    float vbf = bfv[dd], vba = bav[dd], vbe = bev[dd], vbad = badv[dd];
    float bsum = b_ih[r] + b_hh[r];
    float cx = cx0[dd];

    if (tid < 64) {
        HL[tid]  = packh2(hx0[2 * tid], hx0[2 * tid + 1]);
        wpL[tid] = packh2(Wp[2 * tid], Wp[2 * tid + 1]);
    }
    { int u = tid - 64;  if (u >= 0 && u < 32) cwb[0][u] = ((const u32*)cw16)[(b * Sn) * 32 + u]; }
    { int u = tid - 96;  if (u >= 0 && u < 64) kfb[0][u] = ((const u32*)kf16)[(size_t)(b * Sn) * 64 + u]; }
    { int u = tid - 160; if (u >= 0 && u < 64) yab[0][u] = ((const u32*)ya16)[(size_t)(b * Sn) * 64 + u]; }
    if (tid < Sn) prevL[tid] = prev[b * Sn + tid];
    if (tid == 0) bpL = bp[0];
    __syncthreads();

    int pu = tid - 864;          // prefetch role: 0..159 (32 cw + 64 kf + 64 ya)
    u32 pfv = 0;
    int blane = (tid & 63) & ~7; // oct base lane (for gate gather shfls)

    for (int t = 0; t < Sn; ++t) {
        int cur = t & 1;
        // ===== P1: memrec read partial (+issue t+1 prefetch loads) =========
        {
            uint4 cA = ((const uint4*)cwb[cur])[o];
            float lo, hi;
            float p0 = 0, p1 = 0;
            unp2(cA.x, lo, hi); p0 = fmaf(lo, memv[0], p0); p1 = fmaf(hi, memv[1], p1);
            unp2(cA.y, lo, hi); p0 = fmaf(lo, memv[2], p0); p1 = fmaf(hi, memv[3], p1);
            unp2(cA.z, lo, hi); p0 = fmaf(lo, memv[4], p0); p1 = fmaf(hi, memv[5], p1);
            unp2(cA.w, lo, hi); p0 = fmaf(lo, memv[6], p0); p1 = fmaf(hi, memv[7], p1);
            float pr = oct_red(p0 + p1);
            if (o == 0) ((u16*)rbuf)[dd] = __builtin_bit_cast(u16, (f16)pr);
        }
        if (t + 1 < Sn && pu >= 0) {
            if (pu < 32)      pfv = ((const u32*)cw16)[(b * Sn + t + 1) * 32 + pu];
            else if (pu < 96) pfv = ((const u32*)kf16)[(size_t)(b * Sn + t + 1) * 64 + (pu - 32)];
            else              pfv = ((const u32*)ya16)[(size_t)(b * Sn + t + 1) * 64 + (pu - 96)];
        }
        int pv = prevL[t];
        int hrow = (pv >= 0) ? (pv + 1) : t;
        __syncthreads();                                     // B1
        // ===== P2: lstm W_hh·h half-dot + memrec f =========================
        float b0 = 0, b1 = 0, b2 = 0, b3 = 0;
        {
            const uint4* h4 = (const uint4*)(HL + hrow * 64) + half * 8;
#pragma unroll
            for (int u = 0; u < 8; ++u) {
                uint4 x = h4[u];
                b0 = fdot2f(whh[4 * u + 0], x.x, b0);
                b1 = fdot2f(whh[4 * u + 1], x.y, b1);
                b2 = fdot2f(whh[4 * u + 2], x.z, b2);
                b3 = fdot2f(whh[4 * u + 3], x.w, b3);
            }
        }
        {
            uint4 x0 = ((const uint4*)rbuf)[o * 2];
            uint4 x1 = ((const uint4*)rbuf)[o * 2 + 1];
            float a0 = 0, a1 = 0;
            a0 = fdot2f(wfr[0], x0.x, a0);  a1 = fdot2f(wfr[1], x0.y, a1);
            a0 = fdot2f(wfr[2], x0.z, a0);  a1 = fdot2f(wfr[3], x0.w, a1);
            a0 = fdot2f(wfr[4], x1.x, a0);  a1 = fdot2f(wfr[5], x1.y, a1);
            a0 = fdot2f(wfr[6], x1.z, a0);  a1 = fdot2f(wfr[7], x1.w, a1);
            float accf = oct_red(a0 + a1);
            if (o == 0) {
                float kfc, kfd;
                unp2(kfb[cur][dd >> 1], kfc, kfd);
                float fv = tanh_fast(accf + ((dd & 1) ? kfd : kfc) + vbf);
                ((u16*)fbuf)[dd] = __builtin_bit_cast(u16, (f16)fv);
            }
        }
        __syncthreads();                                     // B2
        // ===== P3: lstm W_ih·ft half-dot + memrec we (+park prefetch) ======
        float gv;
        {
            const uint4* f4 = (const uint4*)fbuf + half * 8;
            float g0 = half ? 0.0f : bsum, g1 = 0, g2 = 0, g3 = 0;
#pragma unroll
            for (int u = 0; u < 8; ++u) {
                uint4 x = f4[u];
                g0 = fdot2f(wih[4 * u + 0], x.x, g0);
                g1 = fdot2f(wih[4 * u + 1], x.y, g1);
                g2 = fdot2f(wih[4 * u + 2], x.z, g2);
                g3 = fdot2f(wih[4 * u + 3], x.w, g3);
            }
            float gh = ((g0 + g1) + (g2 + g3)) + ((b0 + b1) + (b2 + b3));
            gv = gh + qdpp<0xB1>(gh);        // pair-reduce (half0+half1)
        }
        {
            uint4 x0 = ((const uint4*)fbuf)[o * 2];
            uint4 x1 = ((const uint4*)fbuf)[o * 2 + 1];
            uint4 wa0 = ((const uint4*)wafS)[tid];
            uint4 wa1 = ((const uint4*)wafS)[1024 + tid];
            float c0 = 0, c1 = 0;
            c0 = fdot2f(wa0.x, x0.x, c0);  c1 = fdot2f(wa0.y, x0.y, c1);
            c0 = fdot2f(wa0.z, x0.z, c0);  c1 = fdot2f(wa0.w, x0.w, c1);
            c0 = fdot2f(wa1.x, x1.x, c0);  c1 = fdot2f(wa1.y, x1.y, c1);
            c0 = fdot2f(wa1.z, x1.z, c0);  c1 = fdot2f(wa1.w, x1.w, c1);
            float accw = oct_red(c0 + c1);
            if (o == 0) {
                float yac, yad;
                unp2(yab[cur][dd >> 1], yac, yad);
                ((u16*)wbuf)[dd] =
                    __builtin_bit_cast(u16, (f16)(accw + ((dd & 1) ? yad : yac) + vba));
            }
        }
        if (t + 1 < Sn && pu >= 0) {
            int nxt = cur ^ 1;
            if (pu < 32)      cwb[nxt][pu] = pfv;
            else if (pu < 96) kfb[nxt][pu - 32] = pfv;
            else              yab[nxt][pu - 96] = pfv;
        }
        __syncthreads();                                     // B3
        // ===== P4: memrec erase/add + mem update + lstm finish =============
        {
            uint4 x0 = ((const uint4*)wbuf)[o * 2];
            uint4 x1 = ((const uint4*)wbuf)[o * 2 + 1];
            uint4 we0 = ((const uint4*)wewS)[tid];
            uint4 we1 = ((const uint4*)wewS)[1024 + tid];
            uint4 wd0 = ((const uint4*)wadwS)[tid];
            uint4 wd1 = ((const uint4*)wadwS)[1024 + tid];
            float e0 = 0, e1 = 0, h0 = 0, h1 = 0;
            e0 = fdot2f(we0.x, x0.x, e0);  h0 = fdot2f(wd0.x, x0.x, h0);
            e1 = fdot2f(we0.y, x0.y, e1);  h1 = fdot2f(wd0.y, x0.y, h1);
            e0 = fdot2f(we0.z, x0.z, e0);  h0 = fdot2f(wd0.z, x0.z, h0);
            e1 = fdot2f(we0.w, x0.w, e1);  h1 = fdot2f(wd0.w, x0.w, h1);
            e0 = fdot2f(we1.x, x1.x, e0);  h0 = fdot2f(wd1.x, x1.x, h0);
            e1 = fdot2f(we1.y, x1.y, e1);  h1 = fdot2f(wd1.y, x1.y, h1);
            e0 = fdot2f(we1.z, x1.z, e0);  h0 = fdot2f(wd1.z, x1.z, h0);
            e1 = fdot2f(we1.w, x1.w, e1);  h1 = fdot2f(wd1.w, x1.w, h1);
            float pe = oct_red(e0 + e1);
            float pa = oct_red(h0 + h1);
            float ev = sig_fast(pe + vbe);
            float av = tanh_fast(pa + vbad);
            uint4 cA = ((const uint4*)cwb[cur])[o];
            float lo, hi;
#define MUP(i0, i1, word) \
            unp2(word, lo, hi); \
            memv[i0] = fmaf(lo, fmaf(-ev, memv[i0], av), memv[i0]); \
            memv[i1] = fmaf(hi, fmaf(-ev, memv[i1], av), memv[i1]);
            MUP(0, 1, cA.x)  MUP(2, 3, cA.y)  MUP(4, 5, cA.z)  MUP(6, 7, cA.w)
#undef MUP
        }
        // lstm finish: lanes g==0 gather f/g/o gates from oct, update state
        {
            float gf_ = __shfl(gv, blane + 2);
            float gg_ = __shfl(gv, blane + 4);
            float go_ = __shfl(gv, blane + 6);
            if (g == 0) {
                float ig = sig_fast(gv), fg = sig_fast(gf_);
                float gt = tanh_fast(gg_), og = sig_fast(go_);
                cx = fmaf(fg, cx, ig * gt);
                float hv = og * tanh_fast(cx);
                if (half == 0)
                    ((u16*)HL)[(t + 1) * 128 + dd] = __builtin_bit_cast(u16, (f16)hv);
            }
        }
    }
    __syncthreads();
    // ---- logits epilogue: 16 waves, strided rows ----
    int w = tid >> 6, lane = tid & 63;
    for (int rr = w; rr < Sn; rr += 16) {
        float acc = fdot2f(HL[(rr + 1) * 64 + lane], wpL[lane], 0.0f);
        for (int off = 32; off; off >>= 1) acc += __shfl_xor(acc, off);
        if (lane == 0) out[b * Sn + rr] = sig_fast(acc + bpL);
    }
}

// ---------------------------------------------------------------------------
extern "C" void kernel_launch(void* const* d_in, const int* in_sizes, int n_in,
                              void* d_out, int out_size, void* d_ws, size_t ws_size,
                              hipStream_t stream) {
    const int*   qseq = (const int*)d_in[0];
    const int*   cseq = (const int*)d_in[1];
    const float* Mk   = (const float*)d_in[2];
    const float* Mv0  = (const float*)d_in[3];
    const float* embc = (const float*)d_in[4];
    const float* embi = (const float*)d_in[5];
    const float* Wf   = (const float*)d_in[6];
    const float* bfv  = (const float*)d_in[7];
    const float* Wa   = (const float*)d_in[8];
    const float* bav  = (const float*)d_in[9];
    const float* We   = (const float*)d_in[10];
    const float* bev  = (const float*)d_in[11];
    const float* Wadd = (const float*)d_in[12];
    const float* badv = (const float*)d_in[13];
    const float* W_ih = (const float*)d_in[14];
    const float* W_hh = (const float*)d_in[15];
    const float* b_ih = (const float*)d_in[16];
    const float* b_hh = (const float*)d_in[17];
    const float* hx0  = (const float*)d_in[18];
    const float* cx0  = (const float*)d_in[19];
    const float* Wp   = (const float*)d_in[20];
    const float* bp   = (const float*)d_in[21];
    float* out = (float*)d_out;

    char* ws = (char*)d_ws;
    u16* cw16 = (u16*)ws;                              // 6,553,600 B
    ulonglong2* codes = (ulonglong2*)(ws + 6553600);   //   819,200 B
    int* prev = (int*)(ws + 7372800);                  //   204,800 B
    u16* kf16 = (u16*)(ws + 7577600);                  // 13,107,200 B
    u16* ya16 = (u16*)(ws + 20684800);                 // 13,107,200 B -> 33.8 MB

    phase0_kernel<<<(Bn * Sn) / 8, 512, 0, stream>>>(qseq, Mk, embc, cw16, codes);
    pre_kernel<<<(Bn * Sn) / 8, 512, 0, stream>>>(Wf, embc, qseq, cseq, 0, kf16);
    pre_kernel<<<(Bn * Sn) / 8, 512, 0, stream>>>(Wa, embi, qseq, cseq, 1, ya16);
    match_kernel<<<Bn, 256, 0, stream>>>(codes, prev);
    fused_kernel<<<Bn, 1024, 0, stream>>>(Mv0, Wf, bfv, Wa, bav, We, bev, Wadd, badv,
                                          W_ih, W_hh, b_ih, b_hh, hx0, cx0, Wp, bp,
                                          cw16, kf16, ya16, prev, out);
}